// Round 18
// baseline (1143.011 us; speedup 1.0000x reference)
//
#include <hip/hip_runtime.h>

// Viterbi decode (CRF): B=128, T=4096, L=64.
// Outputs: score[B] (f32), path[B][T] (written as float labels).
constexpr int kB = 128;
constexpr int kT = 4096;
constexpr int kL = 64;
constexpr int kSeg = 64;     // number of backtrace segments
constexpr int kSegLen = 64;  // rows per segment (last segment has 63)
constexpr float kNeg = -10000.0f;

typedef float f32x4 __attribute__((ext_vector_type(4)));

// ---------------- K1 forward: 4-wave cooperative step -----------------------
// Block = 256 threads (4 waves) per batch; structure proven exact in R16/R17
// (absmax 0.0). R18 change: __syncthreads() -> s_waitcnt lgkmcnt(0) +
// raw s_barrier. __syncthreads emits s_waitcnt vmcnt(0) lgkmcnt(0), draining
// the per-step GLOBAL delta store + feat prefetch loads on the serial chain
// (~200-400cy x 4095 steps). Cross-wave deps are LDS-only (dbuf), so
// lgkmcnt(0) before the barrier is sufficient: each wave's ds_write/ds_read
// are complete before it passes; post-barrier reads cannot see stale data.
// Global stores/loads float free across the barrier (their only consumer is
// the NEXT kernel, ordered by stream).
__device__ __forceinline__ float step4w(const float (&tr)[16], const f32x4* dlp,
                                        float fo) {
  f32x4 v[4];
#pragma unroll
  for (int q = 0; q < 4; ++q) v[q] = dlp[q];   // 4x ds_read_b128
  float m[4];
#pragma unroll
  for (int q = 0; q < 4; ++q) {
    float a0 = tr[4 * q + 0] + v[q].x;
    float a1 = tr[4 * q + 1] + v[q].y;
    float a2 = tr[4 * q + 2] + v[q].z;
    float a3 = tr[4 * q + 3] + v[q].w;
    m[q] = fmaxf(fmaxf(fmaxf(a0, a1), a2), a3);  // v_max3 + v_max
  }
  float part = fmaxf(fmaxf(fmaxf(m[0], m[1]), m[2]), m[3]);
  auto w2 = __builtin_amdgcn_permlane32_swap(__float_as_uint(part),
                                             __float_as_uint(part), false, false);
  float m1 = fmaxf(__uint_as_float(w2[0]), __uint_as_float(w2[1]));  // i ^ 32
  float m2 = fmaxf(m1, __shfl_xor(m1, 16, 64));                      // i ^ 16
  return m2 + fo;
}

__global__ __launch_bounds__(256, 1) void fwd_delta(const float* __restrict__ feats,
                                                    const float* __restrict__ trans,
                                                    float* __restrict__ delta) {
  const int tid = threadIdx.x;
  const int w = tid >> 6;          // wave 0..3
  const int lane = tid & 63;
  const int q = lane >> 4;         // j-quarter
  const int li = lane & 15;
  const int o = 16 * w + li;       // output label owned by this lane quad
  const int b = blockIdx.x;
  const size_t kBL = (size_t)kB * kL;

  // tr[k] = trans[o][16q + k], k=0..15 (contiguous -> float4 loads)
  float tr[16];
#pragma unroll
  for (int k = 0; k < 16; k += 4) {
    float4 v = *reinterpret_cast<const float4*>(trans + o * kL + 16 * q + k);
    tr[k] = v.x; tr[k + 1] = v.y; tr[k + 2] = v.z; tr[k + 3] = v.w;
  }

  __shared__ __align__(16) float dbuf[2][kL];
  const f32x4* dlp0 = reinterpret_cast<const f32x4*>(&dbuf[0][16 * q]);
  const f32x4* dlp1 = reinterpret_cast<const f32x4*>(&dbuf[1][16 * q]);

  // init: t=0 row + dbuf[0]
  if (tid < kL) {
    float dd = (tid == 62) ? 0.0f : kNeg;
    dbuf[0][tid] = dd;
    delta[(size_t)b * kL + tid] = dd;
  }
  __syncthreads();

  const float* fpo = feats + (size_t)b * kT * kL + o;
  float* dro = delta + (size_t)b * kL + o;  // store base; step t at dro[t*kBL]
  // prefetch ring: rows 1..4
  float f0 = fpo[64 * 1], f1 = fpo[64 * 2], f2 = fpo[64 * 3], f3 = fpo[64 * 4];
  const float* pf = fpo + 64 * 5;
  size_t off = kBL;  // t=1

  // LDS-only barrier: own DS ops complete, then s_barrier. No vmcnt drain.
#define LDS_BAR()                                                               \
  {                                                                             \
    asm volatile("s_waitcnt lgkmcnt(0)" ::: "memory");                          \
    __builtin_amdgcn_s_barrier();                                               \
  }

#define STEP(DLP, WBUF, FV)                                                     \
  {                                                                             \
    float dnew = step4w(tr, DLP, FV);                                           \
    if (lane < 16) {                                                            \
      dbuf[WBUF][o] = dnew;                                                     \
      dro[off] = dnew;                                                          \
    }                                                                           \
    off += kBL;                                                                 \
    LDS_BAR();                                                                  \
  }

  for (int it = 0; it < 1022; ++it) {  // steps t=1..4088
    STEP(dlp0, 1, f0) f0 = pf[0];
    STEP(dlp1, 0, f1) f1 = pf[64];
    STEP(dlp0, 1, f2) f2 = pf[128];
    STEP(dlp1, 0, f3) f3 = pf[192];
    pf += 256;
  }
  // remaining: t=4089..4095 (7 steps); pf -> row 4093
  float g0 = pf[0], g1 = pf[64], g2 = pf[128];
  STEP(dlp0, 1, f0)   // 4089
  STEP(dlp1, 0, f1)   // 4090
  STEP(dlp0, 1, f2)   // 4091
  STEP(dlp1, 0, f3)   // 4092
  STEP(dlp0, 1, g0)   // 4093
  STEP(dlp1, 0, g1)   // 4094
  STEP(dlp0, 1, g2)   // 4095
#undef STEP
#undef LDS_BAR
}

// ---------------- K2: recompute backpointers from stored delta --------------
// row r = t*128 + b; delta layout [T][B][L] makes row base = delta + r*64.
__global__ __launch_bounds__(256) void psi_from_delta(const float* __restrict__ delta,
                                                      const float* __restrict__ trans,
                                                      unsigned char* __restrict__ psi) {
  const int lane = threadIdx.x & 63;
  const int w = __builtin_amdgcn_readfirstlane(blockIdx.x * 4 + (threadIdx.x >> 6));
  float tr[kL];
#pragma unroll
  for (int k = 0; k < kL; k += 4) {
    float4 v = *reinterpret_cast<const float4*>(trans + lane * kL + k);
    tr[k] = v.x; tr[k + 1] = v.y; tr[k + 2] = v.z; tr[k + 3] = v.w;
  }
  const int r0 = w * 8;  // 8 rows per wave; grid sized exactly
  for (int rr = 0; rr < 8; ++rr) {
    const int r = r0 + rr;
    const float4* row4 = reinterpret_cast<const float4*>(delta + (size_t)r * kL);
    float bA = -INFINITY, bBv = -INFINITY;
    int iA = 0, iB = 32;
#pragma unroll
    for (int q = 0; q < 8; ++q) {
      float4 dv = row4[q];
      float c; bool g;
      c = tr[4 * q + 0] + dv.x; g = c > bA; bA = g ? c : bA; iA = g ? 4 * q + 0 : iA;
      c = tr[4 * q + 1] + dv.y; g = c > bA; bA = g ? c : bA; iA = g ? 4 * q + 1 : iA;
      c = tr[4 * q + 2] + dv.z; g = c > bA; bA = g ? c : bA; iA = g ? 4 * q + 2 : iA;
      c = tr[4 * q + 3] + dv.w; g = c > bA; bA = g ? c : bA; iA = g ? 4 * q + 3 : iA;
    }
#pragma unroll
    for (int q = 8; q < 16; ++q) {
      float4 dv = row4[q];
      float c; bool g;
      c = tr[4 * q + 0] + dv.x; g = c > bBv; bBv = g ? c : bBv; iB = g ? 4 * q + 0 : iB;
      c = tr[4 * q + 1] + dv.y; g = c > bBv; bBv = g ? c : bBv; iB = g ? 4 * q + 1 : iB;
      c = tr[4 * q + 2] + dv.z; g = c > bBv; bBv = g ? c : bBv; iB = g ? 4 * q + 2 : iB;
      c = tr[4 * q + 3] + dv.w; g = c > bBv; bBv = g ? c : bBv; iB = g ? 4 * q + 3 : iB;
    }
    bool gm = bBv > bA;  // tie -> lower half (first occurrence)
    psi[(size_t)r * kL + lane] = (unsigned char)(gm ? iB : iA);
  }
}

// ---------------- K3: segment composition (in-place psi -> M) ----------------
__global__ __launch_bounds__(256) void seg_compose(unsigned char* psiM,
                                                   unsigned char* __restrict__ C) {
  const int lane = threadIdx.x & 63;
  const int w = blockIdx.x * 4 + (threadIdx.x >> 6);
  const int s = w >> 7;
  const int b = w & 127;
  const int tstart = s * kSegLen;
  const int tend = (tstart + kSegLen < kT) ? tstart + kSegLen : kT - 1;  // last seg: 4095
  const size_t stride = (size_t)kB * kL;
  size_t off = ((size_t)(tend - 1) * kB + b) * kL + lane;
  int m = lane;
  int v = psiM[off];
  for (int t = tend - 1; t > tstart; --t) {
    int vn = psiM[off - stride];          // prefetch next row
    m = __shfl(v, m, 64);                 // m = psi_row[m]
    psiM[off] = (unsigned char)m;         // M[t][b][e] = path[t] | hyp e
    v = vn;
    off -= stride;
  }
  m = __shfl(v, m, 64);
  psiM[off] = (unsigned char)m;
  C[((size_t)s * kB + b) * kL + lane] = (unsigned char)m;  // composed map
}

// ---------------- K4: score, last label, boundary-label scan ----------------
__global__ __launch_bounds__(64) void score_scan(const float* __restrict__ dfin,
                                                 const unsigned char* __restrict__ C,
                                                 int* __restrict__ E,
                                                 float* __restrict__ out) {
  const int b = blockIdx.x;
  const int i = threadIdx.x;
  float d = dfin[(size_t)b * kL + i];
  float m = d;
#pragma unroll
  for (int off = 32; off; off >>= 1) m = fmaxf(m, __shfl_xor(m, off, 64));
  unsigned long long msk = __ballot(d == m);
  int ll = __ffsll(msk) - 1;  // first (lowest) argmax lane
  if (i == 0) {
    out[b] = m;
    out[kB + (size_t)b * kT + (kT - 1)] = (float)ll;
    int lbl = ll;
    for (int s = kSeg - 1; s >= 0; --s) {
      E[s * kB + b] = lbl;                              // label at t_end(s)
      lbl = C[((size_t)s * kB + b) * kL + lbl];         // -> label at t_start(s)
    }
  }
}

// ---------------- K5: parallel path gather ----------------
__global__ __launch_bounds__(256) void path_fill(const unsigned char* __restrict__ M,
                                                 const int* __restrict__ E,
                                                 float* __restrict__ out) {
  const int n = blockIdx.x * 256 + threadIdx.x;  // n = b*4096 + t
  const int b = n >> 12;
  const int t = n & (kT - 1);
  if (t == kT - 1) return;  // written by score_scan
  const int e = E[(t >> 6) * kB + b];
  const unsigned char lab = M[((size_t)t * kB + b) * kL + e];
  out[kB + (size_t)b * kT + t] = (float)lab;
}

extern "C" void kernel_launch(void* const* d_in, const int* in_sizes, int n_in,
                              void* d_out, int out_size, void* d_ws, size_t ws_size,
                              hipStream_t stream) {
  const float* feats = (const float*)d_in[0];
  const float* trans = (const float*)d_in[1];
  float* out = (float*)d_out;
  char* ws = (char*)d_ws;

  const size_t deltaB = (size_t)kT * kB * kL * 4;   // 134,217,728
  const size_t psiB   = (size_t)kT * kB * kL;       //  33,554,432
  const size_t CBy    = (size_t)kSeg * kB * kL;     //     524,288

  float* delta = (float*)ws;
  unsigned char* psi = (unsigned char*)(ws + deltaB);
  unsigned char* C = (unsigned char*)(ws + deltaB + psiB);
  int* E = (int*)(ws + deltaB + psiB + CBy);
  hipLaunchKernelGGL(fwd_delta, dim3(kB), dim3(256), 0, stream, feats, trans, delta);
  hipLaunchKernelGGL(psi_from_delta, dim3(16380), dim3(256), 0, stream, delta, trans, psi);
  hipLaunchKernelGGL(seg_compose, dim3(2048), dim3(256), 0, stream, psi, C);
  hipLaunchKernelGGL(score_scan, dim3(kB), dim3(64), 0, stream,
                     delta + (size_t)(kT - 1) * kB * kL, C, E, out);
  hipLaunchKernelGGL(path_fill, dim3(2048), dim3(256), 0, stream, psi, E, out);
}

// Round 20
// 1017.263 us; speedup vs baseline: 1.1236x; 1.1236x over previous
//
#include <hip/hip_runtime.h>

// Viterbi decode (CRF): B=128, T=4096, L=64.
// Outputs: score[B] (f32), path[B][T] (written as float labels).
constexpr int kB = 128;
constexpr int kT = 4096;
constexpr int kL = 64;
constexpr int kSeg = 64;     // number of backtrace segments
constexpr int kSegLen = 64;  // rows per segment (last segment has 63)
constexpr float kNeg = -10000.0f;

typedef float f32x4 __attribute__((ext_vector_type(4)));

#if __has_builtin(__builtin_amdgcn_permlane16_swap)
#define HAS_PL16 1
#else
#define HAS_PL16 0
#endif

// ---------------- K1 forward: 4-wave cooperative step -----------------------
// Block = 256 threads (4 waves); wave w owns outputs [16w,16w+16); lane quad
// (li, li+16, li+32, li+48) splits j into quarters. Per lane: 4 ds_read_b128
// + 16 adds + tree -> quarter-partial. Combines:
//   i^32: (a,b)=permlane32_swap(p,p); fmaxf(a,b) — proven exact (R16-R18).
//   i^16: (a,b)=permlane16_swap(m,m); fmaxf(a,b) — same symmetric set
//         argument ({a[i],b[i]} = {m[i],m[i^16]} whatever the output order).
//         VALU-only; replaces __shfl_xor's ~120cy DS round-trip (the 2nd
//         LDS RT on the serial chain per R18's decomposition).
// pl16 is verified at runtime (2 chained steps, bitwise, block-uniform flag)
// against the shfl step; fallback runs the shfl loop. Verify leaves no state:
// it writes only dbuf[1], which main-loop step t=1 overwrites.
__device__ __forceinline__ float part4(const float (&tr)[16], const f32x4* dlp) {
  f32x4 v[4];
#pragma unroll
  for (int q = 0; q < 4; ++q) v[q] = dlp[q];   // 4x ds_read_b128
  float m[4];
#pragma unroll
  for (int q = 0; q < 4; ++q) {
    float a0 = tr[4 * q + 0] + v[q].x;
    float a1 = tr[4 * q + 1] + v[q].y;
    float a2 = tr[4 * q + 2] + v[q].z;
    float a3 = tr[4 * q + 3] + v[q].w;
    m[q] = fmaxf(fmaxf(fmaxf(a0, a1), a2), a3);  // v_max3 + v_max
  }
  float part = fmaxf(fmaxf(fmaxf(m[0], m[1]), m[2]), m[3]);
  auto w2 = __builtin_amdgcn_permlane32_swap(__float_as_uint(part),
                                             __float_as_uint(part), false, false);
  return fmaxf(__uint_as_float(w2[0]), __uint_as_float(w2[1]));  // i ^ 32 done
}

__device__ __forceinline__ float step_shfl(const float (&tr)[16], const f32x4* dlp,
                                           float fo) {
  float m1 = part4(tr, dlp);
  return fmaxf(m1, __shfl_xor(m1, 16, 64)) + fo;   // i ^ 16 via DS pipe
}

#if HAS_PL16
__device__ __forceinline__ float step_pl16(const float (&tr)[16], const f32x4* dlp,
                                           float fo) {
  float m1 = part4(tr, dlp);
  auto w2 = __builtin_amdgcn_permlane16_swap(__float_as_uint(m1),
                                             __float_as_uint(m1), false, false);
  return fmaxf(__uint_as_float(w2[0]), __uint_as_float(w2[1])) + fo;  // i^16 VALU
}
#endif

__global__ __launch_bounds__(256, 1) void fwd_delta(const float* __restrict__ feats,
                                                    const float* __restrict__ trans,
                                                    float* __restrict__ delta) {
  const int tid = threadIdx.x;
  const int w = tid >> 6;          // wave 0..3
  const int lane = tid & 63;
  const int q = lane >> 4;         // j-quarter
  const int li = lane & 15;
  const int o = 16 * w + li;       // output label owned by this lane quad
  const int b = blockIdx.x;
  const size_t kBL = (size_t)kB * kL;

  float tr[16];
#pragma unroll
  for (int k = 0; k < 16; k += 4) {
    float4 v = *reinterpret_cast<const float4*>(trans + o * kL + 16 * q + k);
    tr[k] = v.x; tr[k + 1] = v.y; tr[k + 2] = v.z; tr[k + 3] = v.w;
  }

  __shared__ __align__(16) float dbuf[2][kL];
  __shared__ int okf;
  const f32x4* dlp0 = reinterpret_cast<const f32x4*>(&dbuf[0][16 * q]);
  const f32x4* dlp1 = reinterpret_cast<const f32x4*>(&dbuf[1][16 * q]);

  if (tid == 0) okf = 1;
  // init: t=0 row + dbuf[0]
  if (tid < kL) {
    float dd = (tid == 62) ? 0.0f : kNeg;
    dbuf[0][tid] = dd;
    delta[(size_t)b * kL + tid] = dd;
  }
  __syncthreads();

  const float* fpo = feats + (size_t)b * kT * kL + o;
  float* dro = delta + (size_t)b * kL + o;  // store base; step t at dro[off]

  // LDS-only barrier: own DS ops complete, then s_barrier (R18, exact).
#define LDS_BAR()                                                               \
  {                                                                             \
    asm volatile("s_waitcnt lgkmcnt(0)" ::: "memory");                          \
    __builtin_amdgcn_s_barrier();                                               \
  }

  // ---- verify pl16 vs shfl: 2 chained steps, bitwise; state-free ----
  {
    float fA = fpo[64 * 1], fB = fpo[64 * 2];
    float d1 = step_shfl(tr, dlp0, fA);
    if (lane < 16) dbuf[1][o] = d1;
    LDS_BAR();
    float d2 = step_shfl(tr, dlp1, fB);
    LDS_BAR();  // all reads of dbuf[1] complete before the pl16 trial rewrites
#if HAS_PL16
    float p1 = step_pl16(tr, dlp0, fA);
    if (lane < 16) dbuf[1][o] = p1;
    LDS_BAR();
    float p2 = step_pl16(tr, dlp1, fB);
    LDS_BAR();
    bool wok = __all((__float_as_int(p1) == __float_as_int(d1)) &&
                     (__float_as_int(p2) == __float_as_int(d2))) != 0;
    if (!wok && lane == 0) okf = 0;
#else
    (void)d2;
    if (lane == 0) okf = 0;
#endif
    __syncthreads();
  }
  const bool use16 = (okf != 0);

  // ---- main loop: EXACT R18 structure (in-bounds proven) ----
  // dbuf[0] still holds t=0 (verify wrote only dbuf[1]).
  float f0 = fpo[64 * 1], f1 = fpo[64 * 2], f2 = fpo[64 * 3], f3 = fpo[64 * 4];
  const float* pf = fpo + 64 * 5;
  size_t off = kBL;  // t=1

#define STEP(FN, DLP, WBUF, FV)                                                 \
  {                                                                             \
    float dnew = FN(tr, DLP, FV);                                               \
    if (lane < 16) {                                                            \
      dbuf[WBUF][o] = dnew;                                                     \
      dro[off] = dnew;                                                          \
    }                                                                           \
    off += kBL;                                                                 \
    LDS_BAR();                                                                  \
  }

#if HAS_PL16
  if (use16) {
    for (int it = 0; it < 1022; ++it) {  // steps t=1..4088
      STEP(step_pl16, dlp0, 1, f0) f0 = pf[0];
      STEP(step_pl16, dlp1, 0, f1) f1 = pf[64];
      STEP(step_pl16, dlp0, 1, f2) f2 = pf[128];
      STEP(step_pl16, dlp1, 0, f3) f3 = pf[192];
      pf += 256;
    }
    float g0 = pf[0], g1 = pf[64], g2 = pf[128];  // rows 4093..4095
    STEP(step_pl16, dlp0, 1, f0)   // 4089
    STEP(step_pl16, dlp1, 0, f1)   // 4090
    STEP(step_pl16, dlp0, 1, f2)   // 4091
    STEP(step_pl16, dlp1, 0, f3)   // 4092
    STEP(step_pl16, dlp0, 1, g0)   // 4093
    STEP(step_pl16, dlp1, 0, g1)   // 4094
    STEP(step_pl16, dlp0, 1, g2)   // 4095
  } else
#endif
  {
    for (int it = 0; it < 1022; ++it) {
      STEP(step_shfl, dlp0, 1, f0) f0 = pf[0];
      STEP(step_shfl, dlp1, 0, f1) f1 = pf[64];
      STEP(step_shfl, dlp0, 1, f2) f2 = pf[128];
      STEP(step_shfl, dlp1, 0, f3) f3 = pf[192];
      pf += 256;
    }
    float g0 = pf[0], g1 = pf[64], g2 = pf[128];
    STEP(step_shfl, dlp0, 1, f0)
    STEP(step_shfl, dlp1, 0, f1)
    STEP(step_shfl, dlp0, 1, f2)
    STEP(step_shfl, dlp1, 0, f3)
    STEP(step_shfl, dlp0, 1, g0)
    STEP(step_shfl, dlp1, 0, g1)
    STEP(step_shfl, dlp0, 1, g2)
  }
#undef STEP
#undef LDS_BAR
}

// ---------------- K2: recompute backpointers from stored delta --------------
// row r = t*128 + b; delta layout [T][B][L] makes row base = delta + r*64.
__global__ __launch_bounds__(256) void psi_from_delta(const float* __restrict__ delta,
                                                      const float* __restrict__ trans,
                                                      unsigned char* __restrict__ psi) {
  const int lane = threadIdx.x & 63;
  const int w = __builtin_amdgcn_readfirstlane(blockIdx.x * 4 + (threadIdx.x >> 6));
  float tr[kL];
#pragma unroll
  for (int k = 0; k < kL; k += 4) {
    float4 v = *reinterpret_cast<const float4*>(trans + lane * kL + k);
    tr[k] = v.x; tr[k + 1] = v.y; tr[k + 2] = v.z; tr[k + 3] = v.w;
  }
  const int r0 = w * 8;  // 8 rows per wave; grid sized exactly
  for (int rr = 0; rr < 8; ++rr) {
    const int r = r0 + rr;
    const float4* row4 = reinterpret_cast<const float4*>(delta + (size_t)r * kL);
    float bA = -INFINITY, bBv = -INFINITY;
    int iA = 0, iB = 32;
#pragma unroll
    for (int q = 0; q < 8; ++q) {
      float4 dv = row4[q];
      float c; bool g;
      c = tr[4 * q + 0] + dv.x; g = c > bA; bA = g ? c : bA; iA = g ? 4 * q + 0 : iA;
      c = tr[4 * q + 1] + dv.y; g = c > bA; bA = g ? c : bA; iA = g ? 4 * q + 1 : iA;
      c = tr[4 * q + 2] + dv.z; g = c > bA; bA = g ? c : bA; iA = g ? 4 * q + 2 : iA;
      c = tr[4 * q + 3] + dv.w; g = c > bA; bA = g ? c : bA; iA = g ? 4 * q + 3 : iA;
    }
#pragma unroll
    for (int q = 8; q < 16; ++q) {
      float4 dv = row4[q];
      float c; bool g;
      c = tr[4 * q + 0] + dv.x; g = c > bBv; bBv = g ? c : bBv; iB = g ? 4 * q + 0 : iB;
      c = tr[4 * q + 1] + dv.y; g = c > bBv; bBv = g ? c : bBv; iB = g ? 4 * q + 1 : iB;
      c = tr[4 * q + 2] + dv.z; g = c > bBv; bBv = g ? c : bBv; iB = g ? 4 * q + 2 : iB;
      c = tr[4 * q + 3] + dv.w; g = c > bBv; bBv = g ? c : bBv; iB = g ? 4 * q + 3 : iB;
    }
    bool gm = bBv > bA;  // tie -> lower half (first occurrence)
    psi[(size_t)r * kL + lane] = (unsigned char)(gm ? iB : iA);
  }
}

// ---------------- K3: segment composition (in-place psi -> M) ----------------
__global__ __launch_bounds__(256) void seg_compose(unsigned char* psiM,
                                                   unsigned char* __restrict__ C) {
  const int lane = threadIdx.x & 63;
  const int w = blockIdx.x * 4 + (threadIdx.x >> 6);
  const int s = w >> 7;
  const int b = w & 127;
  const int tstart = s * kSegLen;
  const int tend = (tstart + kSegLen < kT) ? tstart + kSegLen : kT - 1;  // last seg: 4095
  const size_t stride = (size_t)kB * kL;
  size_t off = ((size_t)(tend - 1) * kB + b) * kL + lane;
  int m = lane;
  int v = psiM[off];
  for (int t = tend - 1; t > tstart; --t) {
    int vn = psiM[off - stride];          // prefetch next row
    m = __shfl(v, m, 64);                 // m = psi_row[m]
    psiM[off] = (unsigned char)m;         // M[t][b][e] = path[t] | hyp e
    v = vn;
    off -= stride;
  }
  m = __shfl(v, m, 64);
  psiM[off] = (unsigned char)m;
  C[((size_t)s * kB + b) * kL + lane] = (unsigned char)m;  // composed map
}

// ---------------- K4: score, last label, boundary-label scan ----------------
__global__ __launch_bounds__(64) void score_scan(const float* __restrict__ dfin,
                                                 const unsigned char* __restrict__ C,
                                                 int* __restrict__ E,
                                                 float* __restrict__ out) {
  const int b = blockIdx.x;
  const int i = threadIdx.x;
  float d = dfin[(size_t)b * kL + i];
  float m = d;
#pragma unroll
  for (int off = 32; off; off >>= 1) m = fmaxf(m, __shfl_xor(m, off, 64));
  unsigned long long msk = __ballot(d == m);
  int ll = __ffsll(msk) - 1;  // first (lowest) argmax lane
  if (i == 0) {
    out[b] = m;
    out[kB + (size_t)b * kT + (kT - 1)] = (float)ll;
    int lbl = ll;
    for (int s = kSeg - 1; s >= 0; --s) {
      E[s * kB + b] = lbl;                              // label at t_end(s)
      lbl = C[((size_t)s * kB + b) * kL + lbl];         // -> label at t_start(s)
    }
  }
}

// ---------------- K5: parallel path gather ----------------
__global__ __launch_bounds__(256) void path_fill(const unsigned char* __restrict__ M,
                                                 const int* __restrict__ E,
                                                 float* __restrict__ out) {
  const int n = blockIdx.x * 256 + threadIdx.x;  // n = b*4096 + t
  const int b = n >> 12;
  const int t = n & (kT - 1);
  if (t == kT - 1) return;  // written by score_scan
  const int e = E[(t >> 6) * kB + b];
  const unsigned char lab = M[((size_t)t * kB + b) * kL + e];
  out[kB + (size_t)b * kT + t] = (float)lab;
}

extern "C" void kernel_launch(void* const* d_in, const int* in_sizes, int n_in,
                              void* d_out, int out_size, void* d_ws, size_t ws_size,
                              hipStream_t stream) {
  const float* feats = (const float*)d_in[0];
  const float* trans = (const float*)d_in[1];
  float* out = (float*)d_out;
  char* ws = (char*)d_ws;

  const size_t deltaB = (size_t)kT * kB * kL * 4;   // 134,217,728
  const size_t psiB   = (size_t)kT * kB * kL;       //  33,554,432
  const size_t CBy    = (size_t)kSeg * kB * kL;     //     524,288

  float* delta = (float*)ws;
  unsigned char* psi = (unsigned char*)(ws + deltaB);
  unsigned char* C = (unsigned char*)(ws + deltaB + psiB);
  int* E = (int*)(ws + deltaB + psiB + CBy);
  hipLaunchKernelGGL(fwd_delta, dim3(kB), dim3(256), 0, stream, feats, trans, delta);
  hipLaunchKernelGGL(psi_from_delta, dim3(16380), dim3(256), 0, stream, delta, trans, psi);
  hipLaunchKernelGGL(seg_compose, dim3(2048), dim3(256), 0, stream, psi, C);
  hipLaunchKernelGGL(score_scan, dim3(kB), dim3(64), 0, stream,
                     delta + (size_t)(kT - 1) * kB * kL, C, E, out);
  hipLaunchKernelGGL(path_fill, dim3(2048), dim3(256), 0, stream, psi, E, out);
}